// Round 7
// baseline (72.055 us; speedup 1.0000x reference)
//
#include <hip/hip_runtime.h>
#include <cmath>

// 2 graph nodes:
//  N1 prepanchor: blocks 0..R-1:   anchorb[b,a,:] = bf16( sum_seg x / counts[a] )
//                 blocks R..R+255: Wpb = bf16(W_proj)
//                 block  R+256:    M = W_graph ^ hops (hops read on device)
//  N2 fused:      per block (b, dblk, tchunk):
//                   Z[c][dl]  = anchorb[b,c,:] . Wpb[dblk*64+dl,:]   (MFMA, L2 operands)
//                   Y[a'][dl] = sum_c M[a_lo+a',c] * Z[c][dl]        (only anchors in chunk)
//                   out[b,t,dslab] = x[b,t,dslab] + tanh(gate)*Y[assign[t]-a_lo][dl]
// Rationale: anchorb+Wpb+M = 2.6 MB, L2-resident per XCD -> redundant recompute
// across tchunks is cheap; x's second read is L3-absorbed (R5 FETCH evidence).

typedef __attribute__((ext_vector_type(8))) short bf16x8;
typedef __attribute__((ext_vector_type(4))) float f32x4;

#define CH 512   // tokens per fused-block chunk

__device__ inline short f2bf(float f) {            // round-to-nearest-even
    unsigned u = __float_as_uint(f);
    return (short)((u + 0x7FFFu + ((u >> 16) & 1u)) >> 16);
}
__device__ inline int lbound(const int* __restrict__ a, int n, int v) {
    int lo = 0, hi = n;
    while (lo < hi) { int m = (lo + hi) >> 1; if (a[m] < v) lo = m + 1; else hi = m; }
    return lo;
}

// N1: blocks 0..R-1 anchor->bf16; R..R+255 Wp->bf16; R+256 M=W^h.
__global__ __launch_bounds__(256) void prepanchor_kernel(
        const float* __restrict__ x, const float* __restrict__ counts,
        const int* __restrict__ assign, const float* __restrict__ Wg,
        const int* __restrict__ hops, const float* __restrict__ Wp,
        short* __restrict__ anchorb, short* __restrict__ Wpb, float* __restrict__ M,
        int T, int D, int A, int R) {
    __shared__ float s0[4096];
    __shared__ float s1[4096];
    int bid = blockIdx.x, tid = threadIdx.x;
    int rs = D >> 2;
    if (bid < R) {
        int b = bid / A, a = bid - (bid / A) * A;
        int* sT = (int*)s1;
        if (tid < 2) sT[tid] = lbound(assign, T, a + tid);
        __syncthreads();
        int t0 = sT[0], t1 = sT[1];
        float inv = 1.0f / counts[a];
        const float4* x4 = (const float4*)x + (size_t)b * T * rs;
        short4* an4 = (short4*)anchorb + (size_t)bid * rs;
        for (int d4 = tid; d4 < rs; d4 += 256) {
            float4 acc = make_float4(0.f, 0.f, 0.f, 0.f);
            const float4* p = x4 + (size_t)t0 * rs + d4;
            int t = t0;
            for (; t + 8 <= t1; t += 8) {
                float4 v0 = p[0];
                float4 v1 = p[(size_t)rs];
                float4 v2 = p[(size_t)2 * rs];
                float4 v3 = p[(size_t)3 * rs];
                float4 v4 = p[(size_t)4 * rs];
                float4 v5 = p[(size_t)5 * rs];
                float4 v6 = p[(size_t)6 * rs];
                float4 v7 = p[(size_t)7 * rs];
                acc.x += ((v0.x + v1.x) + (v2.x + v3.x)) + ((v4.x + v5.x) + (v6.x + v7.x));
                acc.y += ((v0.y + v1.y) + (v2.y + v3.y)) + ((v4.y + v5.y) + (v6.y + v7.y));
                acc.z += ((v0.z + v1.z) + (v2.z + v3.z)) + ((v4.z + v5.z) + (v6.z + v7.z));
                acc.w += ((v0.w + v1.w) + (v2.w + v3.w)) + ((v4.w + v5.w) + (v6.w + v7.w));
                p += (size_t)8 * rs;
            }
            for (; t < t1; ++t) {
                float4 v = *p;
                acc.x += v.x; acc.y += v.y; acc.z += v.z; acc.w += v.w;
                p += rs;
            }
            short4 o;
            o.x = f2bf(acc.x * inv); o.y = f2bf(acc.y * inv);
            o.z = f2bf(acc.z * inv); o.w = f2bf(acc.w * inv);
            an4[d4] = o;
        }
    } else if (bid < R + 256) {
        long long n8 = (long long)D * D / 8;
        for (long long i = (long long)(bid - R) * 256 + tid; i < n8; i += 256LL * 256LL) {
            const float4* p = (const float4*)Wp + i * 2;
            float4 v0 = p[0], v1 = p[1];
            short4* q = (short4*)Wpb + i * 2;
            short4 o0, o1;
            o0.x = f2bf(v0.x); o0.y = f2bf(v0.y); o0.z = f2bf(v0.z); o0.w = f2bf(v0.w);
            o1.x = f2bf(v1.x); o1.y = f2bf(v1.y); o1.z = f2bf(v1.z); o1.w = f2bf(v1.w);
            q[0] = o0; q[1] = o1;
        }
    } else {
        int n = A * A;
        for (int i = tid; i < n; i += 256) s0[i] = Wg[i];
        int h = hops[0]; if (h < 1) h = 1;
        for (int it = 1; it < h; ++it) {
            __syncthreads();
            for (int i = tid; i < n; i += 256) {
                int r = i / A, c = i - (i / A) * A;
                float s = 0.f;
                for (int k = 0; k < A; ++k) s += Wg[r * A + k] * s0[k * A + c];
                s1[i] = s;
            }
            __syncthreads();
            for (int i = tid; i < n; i += 256) s0[i] = s1[i];
        }
        __syncthreads();
        for (int i = tid; i < n; i += 256) M[i] = s0[i];
    }
}

// N2: grid (B, D/64, ceil(T/CH)); 256 threads = 4 waves (2 cpair x 2 dpair).
// Assumes A == 64, D % 64 == 0 (problem shape).
__global__ __launch_bounds__(256) void fused_kernel(
        const float* __restrict__ x, const short* __restrict__ anchorb,
        const short* __restrict__ Wpb, const float* __restrict__ M,
        const int* __restrict__ assign, const float* __restrict__ gate,
        float* __restrict__ out, int B, int T, int D, int A) {
    __shared__ float Z_lds[64][68];   // 68: 16B-aligned rows, 2-way-max banks
    __shared__ float Y_lds[64][68];
    __shared__ int a_lds[CH];
    int b = blockIdx.x, dblk = blockIdx.y, tch = blockIdx.z;
    int t0 = tch * CH;
    int t1 = t0 + CH; if (t1 > T) t1 = T;
    int len = t1 - t0;
    int tid = threadIdx.x;
    int wave = tid >> 6, lane = tid & 63;
    int rc = lane & 15, kq = lane >> 4;
    int cpair = wave >> 1, dpair = wave & 1;

    for (int i = tid; i < len; i += 256) a_lds[i] = assign[t0 + i];
    __syncthreads();
    int a_lo = a_lds[0], a_hi = a_lds[len - 1];
    int nA = a_hi - a_lo + 1;

    // --- GEMM: Z[c][dl] = anchorb[b,c,:] . Wpb[dblk*64+dl,:]  (wave: 32c x 32d)
    {
        const short* aB0 = anchorb + (size_t)(b * A + cpair * 32 + rc) * D + kq * 8;
        const short* aB1 = aB0 + (size_t)16 * D;
        const short* bB0 = Wpb + (size_t)(dblk * 64 + dpair * 32 + rc) * D + kq * 8;
        const short* bB1 = bB0 + (size_t)16 * D;
        f32x4 acc00 = {0.f,0.f,0.f,0.f}, acc01 = {0.f,0.f,0.f,0.f};
        f32x4 acc10 = {0.f,0.f,0.f,0.f}, acc11 = {0.f,0.f,0.f,0.f};
        for (int k = 0; k < D; k += 32) {
            bf16x8 a0 = *(const bf16x8*)(aB0 + k);
            bf16x8 a1 = *(const bf16x8*)(aB1 + k);
            bf16x8 b0 = *(const bf16x8*)(bB0 + k);
            bf16x8 b1 = *(const bf16x8*)(bB1 + k);
            acc00 = __builtin_amdgcn_mfma_f32_16x16x32_bf16(a0, b0, acc00, 0, 0, 0);
            acc01 = __builtin_amdgcn_mfma_f32_16x16x32_bf16(a0, b1, acc01, 0, 0, 0);
            acc10 = __builtin_amdgcn_mfma_f32_16x16x32_bf16(a1, b0, acc10, 0, 0, 0);
            acc11 = __builtin_amdgcn_mfma_f32_16x16x32_bf16(a1, b1, acc11, 0, 0, 0);
        }
        // D layout: col = lane&15 (B-row), row = kq*4+j (A-row)
        int zr = cpair * 32 + kq * 4;
        int zc = dpair * 32 + rc;
        #pragma unroll
        for (int j = 0; j < 4; ++j) {
            Z_lds[zr + j][zc]           = acc00[j];
            Z_lds[zr + j][zc + 16]      = acc01[j];
            Z_lds[zr + 16 + j][zc]      = acc10[j];
            Z_lds[zr + 16 + j][zc + 16] = acc11[j];
        }
    }
    __syncthreads();

    // --- mix: Y[a'][dl] = sum_c M[a_lo+a', c] * Z[c][dl], only anchors in chunk
    for (int i = tid; i < nA * 16; i += 256) {
        int a_ = i >> 4, d4 = i & 15;
        const float* Mrow = M + (size_t)(a_lo + a_) * A;
        f32x4 acc = {0.f, 0.f, 0.f, 0.f};
        for (int c = 0; c < 64; ++c) {
            float w = Mrow[c];
            f32x4 z = *(const f32x4*)&Z_lds[c][d4 * 4];
            acc[0] += w * z[0]; acc[1] += w * z[1];
            acc[2] += w * z[2]; acc[3] += w * z[3];
        }
        *(f32x4*)&Y_lds[a_][d4 * 4] = acc;
    }
    __syncthreads();

    // --- stream: out slab = x slab + tg * Y[assign[t]-a_lo]
    float tg = tanhf(gate[0]);
    int rs4 = D >> 2;
    const float4* x4 = (const float4*)x;
    float4* o4 = (float4*)out;
    size_t base = (size_t)(b * T + t0) * rs4 + dblk * 16;
    if (len == CH) {
        #pragma unroll 4
        for (int i = tid; i < CH * 16; i += 256) {
            int row = i >> 4, d4 = i & 15;
            int a = a_lds[row] - a_lo;
            size_t idx = base + (size_t)row * rs4 + d4;
            float4 xv = x4[idx];
            f32x4 yv = *(const f32x4*)&Y_lds[a][d4 * 4];
            o4[idx] = make_float4(xv.x + tg * yv[0], xv.y + tg * yv[1],
                                  xv.z + tg * yv[2], xv.w + tg * yv[3]);
        }
    } else {
        for (int i = tid; i < len * 16; i += 256) {
            int row = i >> 4, d4 = i & 15;
            int a = a_lds[row] - a_lo;
            size_t idx = base + (size_t)row * rs4 + d4;
            float4 xv = x4[idx];
            f32x4 yv = *(const f32x4*)&Y_lds[a][d4 * 4];
            o4[idx] = make_float4(xv.x + tg * yv[0], xv.y + tg * yv[1],
                                  xv.z + tg * yv[2], xv.w + tg * yv[3]);
        }
    }
}

extern "C" void kernel_launch(void* const* d_in, const int* in_sizes, int n_in,
                              void* d_out, int out_size, void* d_ws, size_t ws_size,
                              hipStream_t stream) {
    const float* x      = (const float*)d_in[0];
    const float* Wp     = (const float*)d_in[1];
    const float* gate   = (const float*)d_in[2];
    const int*   assign = (const int*)d_in[3];
    const float* Wg     = (const float*)d_in[4];
    const float* counts = (const float*)d_in[5];
    const int*   hops   = (const int*)d_in[6];
    float* out = (float*)d_out;

    int T = in_sizes[3];
    int A = in_sizes[5];
    int D = (int)(sqrt((double)in_sizes[1]) + 0.5);
    int B = (int)(in_sizes[0] / ((long long)T * D));
    int R = B * A;

    // workspace: M (A*A f32) | anchorb (R*D bf16) | Wpb (D*D bf16)
    float* M       = (float*)d_ws;
    short* anchorb = (short*)(M + (size_t)A * A);
    short* Wpb     = anchorb + (size_t)R * D;

    prepanchor_kernel<<<R + 257, 256, 0, stream>>>(x, counts, assign, Wg, hops, Wp,
                                                   anchorb, Wpb, M, T, D, A, R);
    dim3 g(B, D / 64, (T + CH - 1) / CH);
    fused_kernel<<<g, 256, 0, stream>>>(x, anchorb, Wpb, M, assign, gate, out,
                                        B, T, D, A);
}

// Round 8
// 64.687 us; speedup vs baseline: 1.1139x; 1.1139x over previous
//
#include <hip/hip_runtime.h>
#include <cmath>

// 3 graph nodes:
//  N1 prepanchor: blocks 0..2R-1:     anchorb[b,a,:] = bf16( sum_seg x / counts[a] )
//                                     (2 blocks per (b,a): d-halves; thread-halves split t)
//                 blocks 2R..2R+255:  Wpb = bf16(W_proj)
//                 block  2R+256:      M = W_graph ^ hops (hops read on device)
//  N2 ymix: per block (b, dblk): Z[c][dl] = anchorb[b,c,:] . Wpb[dblk*64+dl,:] (MFMA)
//           then Y[b,a,dslab] = sum_c M[a,c] * Z[c][dl]  (in-LDS mix, f32 Y to global)
//  N3 out:  out[b,t,:] = x[b,t,:] + tanh(gate) * Y[b,assign[t],:]  (2048 blocks)

typedef __attribute__((ext_vector_type(8))) short bf16x8;
typedef __attribute__((ext_vector_type(4))) float f32x4;

#define OROWS 8

__device__ inline short f2bf(float f) {            // round-to-nearest-even
    unsigned u = __float_as_uint(f);
    return (short)((u + 0x7FFFu + ((u >> 16) & 1u)) >> 16);
}
__device__ inline int lbound(const int* __restrict__ a, int n, int v) {
    int lo = 0, hi = n;
    while (lo < hi) { int m = (lo + hi) >> 1; if (a[m] < v) lo = m + 1; else hi = m; }
    return lo;
}

// N1
__global__ __launch_bounds__(256) void prepanchor_kernel(
        const float* __restrict__ x, const float* __restrict__ counts,
        const int* __restrict__ assign, const float* __restrict__ Wg,
        const int* __restrict__ hops, const float* __restrict__ Wp,
        short* __restrict__ anchorb, short* __restrict__ Wpb, float* __restrict__ M,
        int T, int D, int A, int R) {
    __shared__ float s0[4096];
    __shared__ float s1[4096];
    int bid = blockIdx.x, tid = threadIdx.x;
    int rs = D >> 2;                                   // float4 per row (256)
    if (bid < 2 * R) {
        int u = bid >> 1, half = bid & 1;
        int b = u / A, a = u - (u / A) * A;
        int* sT = (int*)s1;
        if (tid < 2) sT[tid] = lbound(assign, T, a + tid);
        __syncthreads();
        int t0 = sT[0], t1 = sT[1];
        float inv = 1.0f / counts[a];
        int d4 = half * (rs >> 1) + (tid & 127);       // this block's column
        int tp = tid >> 7;                             // 0/1: t-parity split
        const float4* x4 = (const float4*)x + (size_t)b * T * rs;
        float4 acc = make_float4(0.f, 0.f, 0.f, 0.f);
        int t = t0 + tp;
        const float4* p = x4 + (size_t)t * rs + d4;
        for (; t + 14 < t1; t += 16) {                 // 8 loads, stride 2 rows
            float4 v0 = p[0];
            float4 v1 = p[(size_t)2 * rs];
            float4 v2 = p[(size_t)4 * rs];
            float4 v3 = p[(size_t)6 * rs];
            float4 v4 = p[(size_t)8 * rs];
            float4 v5 = p[(size_t)10 * rs];
            float4 v6 = p[(size_t)12 * rs];
            float4 v7 = p[(size_t)14 * rs];
            acc.x += ((v0.x + v1.x) + (v2.x + v3.x)) + ((v4.x + v5.x) + (v6.x + v7.x));
            acc.y += ((v0.y + v1.y) + (v2.y + v3.y)) + ((v4.y + v5.y) + (v6.y + v7.y));
            acc.z += ((v0.z + v1.z) + (v2.z + v3.z)) + ((v4.z + v5.z) + (v6.z + v7.z));
            acc.w += ((v0.w + v1.w) + (v2.w + v3.w)) + ((v4.w + v5.w) + (v6.w + v7.w));
            p += (size_t)16 * rs;
        }
        for (; t < t1; t += 2) {
            float4 v = *p;
            acc.x += v.x; acc.y += v.y; acc.z += v.z; acc.w += v.w;
            p += (size_t)2 * rs;
        }
        float4* sA = (float4*)s0;
        sA[tid] = acc;
        __syncthreads();
        if (tid < 128) {
            float4 o = sA[tid];
            float4 q = sA[tid + 128];
            o.x = (o.x + q.x) * inv; o.y = (o.y + q.y) * inv;
            o.z = (o.z + q.z) * inv; o.w = (o.w + q.w) * inv;
            short4 ob;
            ob.x = f2bf(o.x); ob.y = f2bf(o.y); ob.z = f2bf(o.z); ob.w = f2bf(o.w);
            ((short4*)anchorb)[(size_t)u * rs + d4] = ob;
        }
    } else if (bid < 2 * R + 256) {
        long long n8 = (long long)D * D / 8;
        for (long long i = (long long)(bid - 2 * R) * 256 + tid; i < n8; i += 256LL * 256LL) {
            const float4* p = (const float4*)Wp + i * 2;
            float4 v0 = p[0], v1 = p[1];
            short4* q = (short4*)Wpb + i * 2;
            short4 o0, o1;
            o0.x = f2bf(v0.x); o0.y = f2bf(v0.y); o0.z = f2bf(v0.z); o0.w = f2bf(v0.w);
            o1.x = f2bf(v1.x); o1.y = f2bf(v1.y); o1.z = f2bf(v1.z); o1.w = f2bf(v1.w);
            q[0] = o0; q[1] = o1;
        }
    } else {
        int n = A * A;
        for (int i = tid; i < n; i += 256) s0[i] = Wg[i];
        int h = hops[0]; if (h < 1) h = 1;
        for (int it = 1; it < h; ++it) {
            __syncthreads();
            for (int i = tid; i < n; i += 256) {
                int r = i / A, c = i - (i / A) * A;
                float s = 0.f;
                for (int k = 0; k < A; ++k) s += Wg[r * A + k] * s0[k * A + c];
                s1[i] = s;
            }
            __syncthreads();
            for (int i = tid; i < n; i += 256) s0[i] = s1[i];
        }
        __syncthreads();
        for (int i = tid; i < n; i += 256) M[i] = s0[i];
    }
}

// N2: grid (B, D/64); 256 threads = 4 waves (2 cpair x 2 dpair). Assumes A == 64.
__global__ __launch_bounds__(256) void ymix_kernel(
        const short* __restrict__ anchorb, const short* __restrict__ Wpb,
        const float* __restrict__ M, float* __restrict__ Y, int D, int A) {
    __shared__ float Z_lds[64][68];
    int b = blockIdx.x, dblk = blockIdx.y;
    int tid = threadIdx.x;
    int wave = tid >> 6, lane = tid & 63;
    int rc = lane & 15, kq = lane >> 4;
    int cpair = wave >> 1, dpair = wave & 1;

    // GEMM: Z[c][dl] = anchorb[b,c,:] . Wpb[dblk*64+dl,:]  (verified R7 layout)
    {
        const short* aB0 = anchorb + (size_t)(b * A + cpair * 32 + rc) * D + kq * 8;
        const short* aB1 = aB0 + (size_t)16 * D;
        const short* bB0 = Wpb + (size_t)(dblk * 64 + dpair * 32 + rc) * D + kq * 8;
        const short* bB1 = bB0 + (size_t)16 * D;
        f32x4 acc00 = {0.f,0.f,0.f,0.f}, acc01 = {0.f,0.f,0.f,0.f};
        f32x4 acc10 = {0.f,0.f,0.f,0.f}, acc11 = {0.f,0.f,0.f,0.f};
        for (int k = 0; k < D; k += 32) {
            bf16x8 a0 = *(const bf16x8*)(aB0 + k);
            bf16x8 a1 = *(const bf16x8*)(aB1 + k);
            bf16x8 b0 = *(const bf16x8*)(bB0 + k);
            bf16x8 b1 = *(const bf16x8*)(bB1 + k);
            acc00 = __builtin_amdgcn_mfma_f32_16x16x32_bf16(a0, b0, acc00, 0, 0, 0);
            acc01 = __builtin_amdgcn_mfma_f32_16x16x32_bf16(a0, b1, acc01, 0, 0, 0);
            acc10 = __builtin_amdgcn_mfma_f32_16x16x32_bf16(a1, b0, acc10, 0, 0, 0);
            acc11 = __builtin_amdgcn_mfma_f32_16x16x32_bf16(a1, b1, acc11, 0, 0, 0);
        }
        int zr = cpair * 32 + kq * 4;
        int zc = dpair * 32 + rc;
        #pragma unroll
        for (int j = 0; j < 4; ++j) {
            Z_lds[zr + j][zc]           = acc00[j];
            Z_lds[zr + j][zc + 16]      = acc01[j];
            Z_lds[zr + 16 + j][zc]      = acc10[j];
            Z_lds[zr + 16 + j][zc + 16] = acc11[j];
        }
    }
    __syncthreads();

    // mix: Y[b,a,dblk*64+dl] = sum_c M[a,c] * Z[c][dl]   (1024 items, 4 iters)
    for (int i = tid; i < A * 16; i += 256) {
        int a_ = i >> 4, d4 = i & 15;
        const float* Mrow = M + (size_t)a_ * A;
        f32x4 acc = {0.f, 0.f, 0.f, 0.f};
        for (int c = 0; c < 64; ++c) {
            float w = Mrow[c];
            f32x4 z = *(const f32x4*)&Z_lds[c][d4 * 4];
            acc[0] += w * z[0]; acc[1] += w * z[1];
            acc[2] += w * z[2]; acc[3] += w * z[3];
        }
        *(f32x4*)&Y[((size_t)b * A + a_) * D + dblk * 64 + d4 * 4] = acc;
    }
}

// N3: out[b,t,:] = x[b,t,:] + tg * Y[b,assign[t],:]   (B*T/OROWS = 2048 blocks)
__global__ __launch_bounds__(256) void out_kernel(
        const float* __restrict__ x, const float* __restrict__ Y,
        const int* __restrict__ assign, const float* __restrict__ gate,
        float* __restrict__ out, int T, int D, int A) {
    float tg = tanhf(gate[0]);
    int rs = D >> 2;
    int bt0 = blockIdx.x * OROWS;
    const float4* x4 = (const float4*)x;
    const float4* y4 = (const float4*)Y;
    float4* o4 = (float4*)out;
    #pragma unroll
    for (int r = 0; r < OROWS; ++r) {
        int bt = bt0 + r;
        int b = bt / T;
        int t = bt - b * T;
        int a = assign[t];
        const float4* yr = y4 + ((size_t)b * A + a) * rs;
        for (int d4 = threadIdx.x; d4 < rs; d4 += 256) {
            float4 xv = x4[(size_t)bt * rs + d4];
            float4 yv = yr[d4];
            o4[(size_t)bt * rs + d4] = make_float4(xv.x + tg * yv.x, xv.y + tg * yv.y,
                                                   xv.z + tg * yv.z, xv.w + tg * yv.w);
        }
    }
}

extern "C" void kernel_launch(void* const* d_in, const int* in_sizes, int n_in,
                              void* d_out, int out_size, void* d_ws, size_t ws_size,
                              hipStream_t stream) {
    const float* x      = (const float*)d_in[0];
    const float* Wp     = (const float*)d_in[1];
    const float* gate   = (const float*)d_in[2];
    const int*   assign = (const int*)d_in[3];
    const float* Wg     = (const float*)d_in[4];
    const float* counts = (const float*)d_in[5];
    const int*   hops   = (const int*)d_in[6];
    float* out = (float*)d_out;

    int T = in_sizes[3];
    int A = in_sizes[5];
    int D = (int)(sqrt((double)in_sizes[1]) + 0.5);
    int B = (int)(in_sizes[0] / ((long long)T * D));
    int R = B * A;

    // workspace: M (A*A f32) | Y (R*D f32) | anchorb (R*D bf16) | Wpb (D*D bf16)
    float* M       = (float*)d_ws;
    float* Y       = M + (size_t)A * A;
    short* anchorb = (short*)(Y + (size_t)R * D);
    short* Wpb     = anchorb + (size_t)R * D;

    prepanchor_kernel<<<2 * R + 257, 256, 0, stream>>>(x, counts, assign, Wg, hops, Wp,
                                                       anchorb, Wpb, M, T, D, A, R);
    dim3 g(B, D / 64);
    ymix_kernel<<<g, 256, 0, stream>>>(anchorb, Wpb, M, Y, D, A);
    out_kernel<<<B * T / OROWS, 256, 0, stream>>>(x, Y, assign, gate, out, T, D, A);
}